// Round 10
// baseline (410.178 us; speedup 1.0000x reference)
//
#include <hip/hip_runtime.h>

#define NN 50000
#define NE 800000
#define EH (NE + NN)   // 850000 edges incl. self-loops
#define HD 128
#define NB 196         // ceil(NN/256)
#define NCH 4          // column chunks
#define CPW 32         // cols per chunk (bf16 row = 64 B = one cache line)
#define PSTRH ((NN + 1) * CPW)  // halves per panel = 1600032 (row NN = dummy zeros)
// XCD partitioning of the graph build
#define NPART 8
#define PSZ (NN / NPART)       // 6250 nodes per part
#define BPP 16                 // blocks per part
// windowed counting-sort: sort by degree WITHIN each 1024-node window
#define WLOG 10
#define NWIN 49
#define DBIN 64
#define DSUB 4
#define NH2 (NWIN * DBIN * DSUB)   // 12544 bins
#define NH2B ((NH2 + 255) / 256)   // 49 scan blocks

__device__ __forceinline__ unsigned short f2bf(float f) {
  union { float f; unsigned int u; } v; v.f = f;
  unsigned int r = v.u + 0x7FFFu + ((v.u >> 16) & 1u);   // RNE
  return (unsigned short)(r >> 16);
}

// ---------------- graph build ----------------
__global__ void k_init_deg(int* __restrict__ deg) {
  int i = blockIdx.x * 256 + threadIdx.x;
  if (i < NN) deg[i] = 1;   // self-loop contributes 1
}

// XCD-partitioned degree count: part = bid&7 owns nodes [part*PSZ, +PSZ).
// LDS histogram per block -> sequential atomic flush (no random device atomics).
__global__ __launch_bounds__(256) void k_count_part(const int* __restrict__ dst,
                                                    int* __restrict__ deg) {
  __shared__ int h[PSZ];   // 25 KB
  const int part = blockIdx.x & (NPART - 1);
  const int sub = blockIdx.x >> 3;
  const int lo = part * PSZ;
  for (int i = threadIdx.x; i < PSZ; i += 256) h[i] = 0;
  __syncthreads();
  for (int e = sub * 256 + threadIdx.x; e < NE; e += BPP * 256) {
    int d = dst[e];
    unsigned int r = (unsigned int)(d - lo);
    if (r < PSZ) atomicAdd(&h[r], 1);
  }
  __syncthreads();
  for (int i = threadIdx.x; i < PSZ; i += 256) {
    int c = h[i];
    if (c) atomicAdd(&deg[lo + i], c);
  }
}

// per-block sums of PADDED degree ((d+3)&~3)
__global__ __launch_bounds__(256) void k_blocksum_pad(const int* __restrict__ deg,
                                                      int* __restrict__ partial) {
  int i = blockIdx.x * 256 + threadIdx.x;
  int v = (i < NN) ? ((deg[i] + 3) & ~3) : 0;
  #pragma unroll
  for (int off = 32; off >= 1; off >>= 1) v += __shfl_down(v, off);
  __shared__ int ws[4];
  if ((threadIdx.x & 63) == 0) ws[threadIdx.x >> 6] = v;
  __syncthreads();
  if (threadIdx.x == 0) partial[blockIdx.x] = ws[0] + ws[1] + ws[2] + ws[3];
}

__global__ __launch_bounds__(256) void k_blocksum(const int* __restrict__ in,
                                                  int* __restrict__ partial, int nelem) {
  int i = blockIdx.x * 256 + threadIdx.x;
  int v = (i < nelem) ? in[i] : 0;
  #pragma unroll
  for (int off = 32; off >= 1; off >>= 1) v += __shfl_down(v, off);
  __shared__ int ws[4];
  if ((threadIdx.x & 63) == 0) ws[threadIdx.x >> 6] = v;
  __syncthreads();
  if (threadIdx.x == 0) partial[blockIdx.x] = ws[0] + ws[1] + ws[2] + ws[3];
}

__global__ __launch_bounds__(256) void k_scanp(int* __restrict__ data, int n) {
  __shared__ int lds[256];
  int t = threadIdx.x;
  int v = (t < n) ? data[t] : 0;
  lds[t] = v;
  __syncthreads();
  #pragma unroll
  for (int off = 1; off < 256; off <<= 1) {
    int u = (t >= off) ? lds[t - off] : 0;
    __syncthreads();
    lds[t] += u;
    __syncthreads();
  }
  if (t < n) data[t] = lds[t] - v;   // exclusive
}

// row_start (padded, 4-aligned) / cursor + fused dis = rsqrt(real deg)
__global__ __launch_bounds__(256) void k_scatter(const int* __restrict__ deg,
                                                 const int* __restrict__ partial,
                                                 int* __restrict__ row_start,
                                                 int* __restrict__ cursor,
                                                 float* __restrict__ dis) {
  __shared__ int lds[256];
  int t = threadIdx.x;
  int i = blockIdx.x * 256 + t;
  int vr = (i < NN) ? deg[i] : 0;
  int v = (vr + 3) & ~3;
  lds[t] = v;
  __syncthreads();
  #pragma unroll
  for (int off = 1; off < 256; off <<= 1) {
    int u = (t >= off) ? lds[t - off] : 0;
    __syncthreads();
    lds[t] += u;
    __syncthreads();
  }
  int ex = lds[t] - v + partial[blockIdx.x];
  if (i < NN) {
    row_start[i] = ex;
    cursor[i] = ex;
    dis[i] = rsqrtf((float)vr);   // deg >= 1 always
    if (i == NN - 1) row_start[NN] = ex + v;
  }
}

// XCD-partitioned CSR fill: each part's cursor atomics + csr stores stay in one
// XCD's L2 (contiguous ~425 KB region) -> stores coalesce, no partial-line HBM writes.
__global__ __launch_bounds__(256) void k_fill_part(const int* __restrict__ src,
                                                   const int* __restrict__ dst,
                                                   int* __restrict__ cursor,
                                                   int* __restrict__ csr_src) {
  const int part = blockIdx.x & (NPART - 1);
  const int sub = blockIdx.x >> 3;
  const int lo = part * PSZ;
  for (int e = sub * 256 + threadIdx.x; e < EH; e += BPP * 256) {
    int d = (e < NE) ? dst[e] : (e - NE);
    unsigned int r = (unsigned int)(d - lo);
    if (r < PSZ) {
      int s = (e < NE) ? src[e] : d;
      int pos = atomicAdd(&cursor[d], 1);
      csr_src[pos] = s;
    }
  }
}

// fill padding slots (up to 3 per node) with dummy row index NN
__global__ void k_pad(const int* __restrict__ deg, const int* __restrict__ row_start,
                      int* __restrict__ csr_src) {
  int n = blockIdx.x * 256 + threadIdx.x;
  if (n < NN) {
    int d = deg[n];
    int s = row_start[n] + d;
    int e = row_start[n] + ((d + 3) & ~3);
    for (int q = s; q < e; ++q) csr_src[q] = NN;
  }
}

// ------------- windowed degree counting-sort ----------------------------------
__device__ __forceinline__ int sort_bin(int i, int d) {
  if (d > DBIN - 1) d = DBIN - 1;
  return (((i >> WLOG) * DBIN + d) * DSUB) + (i & (DSUB - 1));
}

// also zeroes the panels' dummy rows (runs before any GEMM writes panels)
__global__ void k_hist2(const int* __restrict__ deg, int* __restrict__ h,
                        unsigned short* __restrict__ panels) {
  int i = blockIdx.x * 256 + threadIdx.x;
  if (i < NCH * CPW) {   // 128 threads zero 4 x 32 dummy halves
    int pl = i >> 5;
    panels[(size_t)pl * PSTRH + (size_t)NN * CPW + (i & 31)] = 0;
  }
  if (i < NN) atomicAdd(&h[sort_bin(i, deg[i])], 1);
}

__global__ __launch_bounds__(256) void k_excl(int* __restrict__ data,
                                              const int* __restrict__ partial, int nelem) {
  __shared__ int lds[256];
  int t = threadIdx.x;
  int i = blockIdx.x * 256 + t;
  int v = (i < nelem) ? data[i] : 0;
  lds[t] = v;
  __syncthreads();
  #pragma unroll
  for (int off = 1; off < 256; off <<= 1) {
    int u = (t >= off) ? lds[t - off] : 0;
    __syncthreads();
    lds[t] += u;
    __syncthreads();
  }
  if (i < nelem) data[i] = lds[t] - v + partial[blockIdx.x];
}

__global__ void k_perm2(const int* __restrict__ deg, int* __restrict__ h,
                        int* __restrict__ perm) {
  int i = blockIdx.x * 256 + threadIdx.x;
  if (i < NN) {
    int pos = atomicAdd(&h[sort_bin(i, deg[i])], 1);
    perm[pos] = i;
  }
}

// ------- dense GEMM: Cpanels(bf16) = dis[row] * (A[NN,128] @ W[128,128]) ----------
#define GR 128
__global__ __launch_bounds__(256, 1) void k_gemm(const float* __restrict__ A,
                                                 const float* __restrict__ W,
                                                 const float* __restrict__ dis,
                                                 unsigned short* __restrict__ C) {
  __shared__ float As[GR][HD + 4];
  __shared__ float Ws[HD * HD];
  const int tid = threadIdx.x;
  const int r0 = blockIdx.x * GR;
  #pragma unroll
  for (int m = 0; m < 16; ++m) {
    int f = tid + m * 256;
    ((float4*)Ws)[f] = ((const float4*)W)[f];
  }
  #pragma unroll
  for (int m = 0; m < 16; ++m) {
    int f = tid + m * 256;
    int r = f >> 5, c4 = f & 31;
    int gr_ = r0 + r;
    float4 v = make_float4(0.f, 0.f, 0.f, 0.f);
    if (gr_ < NN) v = ((const float4*)A)[gr_ * 32 + c4];
    *(float4*)&As[r][c4 * 4] = v;
  }
  __syncthreads();
  const int tg = tid >> 4;
  const int tc = tid & 15;
  const int cc = tc * 4;
  float acc[8][8];
  #pragma unroll
  for (int j = 0; j < 8; ++j)
    #pragma unroll
    for (int c = 0; c < 8; ++c) acc[j][c] = 0.f;

  for (int k = 0; k < HD; k += 4) {
    float4 a[8];
    #pragma unroll
    for (int j = 0; j < 8; ++j) a[j] = *(const float4*)&As[tg + 16 * j][k];
    #pragma unroll
    for (int kk = 0; kk < 4; ++kk) {
      float4 w0 = *(const float4*)&Ws[(k + kk) * HD + cc];
      float4 w1 = *(const float4*)&Ws[(k + kk) * HD + cc + 64];
      #pragma unroll
      for (int j = 0; j < 8; ++j) {
        float av = (kk == 0) ? a[j].x : (kk == 1) ? a[j].y : (kk == 2) ? a[j].z : a[j].w;
        acc[j][0] += av * w0.x; acc[j][1] += av * w0.y;
        acc[j][2] += av * w0.z; acc[j][3] += av * w0.w;
        acc[j][4] += av * w1.x; acc[j][5] += av * w1.y;
        acc[j][6] += av * w1.z; acc[j][7] += av * w1.w;
      }
    }
  }
  const int p0 = cc >> 5;          // cols cc..cc+3 -> panel 0/1
  const int pc0 = cc & 31;
  #pragma unroll
  for (int j = 0; j < 8; ++j) {
    int row = r0 + tg + 16 * j;
    if (row < NN) {
      const float dsc = dis[row];
      ushort4 u0, u1;
      u0.x = f2bf(acc[j][0] * dsc); u0.y = f2bf(acc[j][1] * dsc);
      u0.z = f2bf(acc[j][2] * dsc); u0.w = f2bf(acc[j][3] * dsc);
      u1.x = f2bf(acc[j][4] * dsc); u1.y = f2bf(acc[j][5] * dsc);
      u1.z = f2bf(acc[j][6] * dsc); u1.w = f2bf(acc[j][7] * dsc);
      *(ushort4*)&C[(size_t)p0 * PSTRH + (size_t)row * CPW + pc0] = u0;
      *(ushort4*)&C[(size_t)(p0 + 2) * PSTRH + (size_t)row * CPW + pc0] = u1;
    }
  }
}

// ---------------- CSR gather-aggregate (bf16 panels, window-sorted) ---------------
__device__ __forceinline__ void bacc(float* a, uint4 q) {
  union { unsigned int u; float f; } t;
  t.u = q.x << 16;          a[0] += t.f;
  t.u = q.x & 0xFFFF0000u;  a[1] += t.f;
  t.u = q.y << 16;          a[2] += t.f;
  t.u = q.y & 0xFFFF0000u;  a[3] += t.f;
  t.u = q.z << 16;          a[4] += t.f;
  t.u = q.z & 0xFFFF0000u;  a[5] += t.f;
  t.u = q.w << 16;          a[6] += t.f;
  t.u = q.w & 0xFFFF0000u;  a[7] += t.f;
}

__global__ __launch_bounds__(256) void k_agg(const unsigned short* __restrict__ Tpanels,
                                             const float* __restrict__ dis,
                                             const int* __restrict__ row_start,
                                             const int* __restrict__ csr_src,
                                             const int* __restrict__ perm,
                                             const float* __restrict__ bias,
                                             float* __restrict__ out) {
  const int tid = threadIdx.x;
  const int chunk = blockIdx.x & (NCH - 1);
  const int idx = (blockIdx.x >> 2) * 64 + (tid >> 2);
  if (idx >= NN) return;
  const int n = perm[idx];
  const int c8 = tid & 3;                       // 8-col slot within chunk
  const unsigned short* __restrict__ P = Tpanels + (size_t)chunk * PSTRH;
  const int4* __restrict__ csr4 = (const int4*)csr_src;

  const int jb = row_start[n] >> 2, je = row_start[n + 1] >> 2;   // 4-aligned
  float a0[8] = {0,0,0,0,0,0,0,0};
  float a1[8] = {0,0,0,0,0,0,0,0};
  int j = jb;
  for (; j + 2 <= je; j += 2) {
    int4 sA = csr4[j], sB = csr4[j + 1];
    uint4 q0 = *(const uint4*)&P[(size_t)sA.x * CPW + c8 * 8];
    uint4 q1 = *(const uint4*)&P[(size_t)sA.y * CPW + c8 * 8];
    uint4 q2 = *(const uint4*)&P[(size_t)sA.z * CPW + c8 * 8];
    uint4 q3 = *(const uint4*)&P[(size_t)sA.w * CPW + c8 * 8];
    uint4 q4 = *(const uint4*)&P[(size_t)sB.x * CPW + c8 * 8];
    uint4 q5 = *(const uint4*)&P[(size_t)sB.y * CPW + c8 * 8];
    uint4 q6 = *(const uint4*)&P[(size_t)sB.z * CPW + c8 * 8];
    uint4 q7 = *(const uint4*)&P[(size_t)sB.w * CPW + c8 * 8];
    bacc(a0, q0); bacc(a1, q1); bacc(a0, q2); bacc(a1, q3);
    bacc(a0, q4); bacc(a1, q5); bacc(a0, q6); bacc(a1, q7);
  }
  if (j < je) {
    int4 sA = csr4[j];
    uint4 q0 = *(const uint4*)&P[(size_t)sA.x * CPW + c8 * 8];
    uint4 q1 = *(const uint4*)&P[(size_t)sA.y * CPW + c8 * 8];
    uint4 q2 = *(const uint4*)&P[(size_t)sA.z * CPW + c8 * 8];
    uint4 q3 = *(const uint4*)&P[(size_t)sA.w * CPW + c8 * 8];
    bacc(a0, q0); bacc(a1, q1); bacc(a0, q2); bacc(a1, q3);
  }
  const float dn = dis[n];
  const int cb = chunk * CPW + c8 * 8;
  const float4 b0 = *(const float4*)&bias[cb];
  const float4 b1 = *(const float4*)&bias[cb + 4];
  float r[8];
  #pragma unroll
  for (int i = 0; i < 8; ++i) r[i] = (a0[i] + a1[i]) * dn;
  r[0] += b0.x; r[1] += b0.y; r[2] += b0.z; r[3] += b0.w;
  r[4] += b1.x; r[5] += b1.y; r[6] += b1.z; r[7] += b1.w;
  #pragma unroll
  for (int i = 0; i < 8; ++i) r[i] = (r[i] >= 0.f) ? r[i] : 0.01f * r[i];
  float* o = out + (size_t)n * HD + cb;
  *(float4*)o = make_float4(r[0], r[1], r[2], r[3]);
  *(float4*)(o + 4) = make_float4(r[4], r[5], r[6], r[7]);
}

extern "C" void kernel_launch(void* const* d_in, const int* in_sizes, int n_in,
                              void* d_out, int out_size, void* d_ws, size_t ws_size,
                              hipStream_t stream) {
  const float* x  = (const float*)d_in[0];
  const int*   ei = (const int*)d_in[1];
  const float* W0 = (const float*)d_in[2];
  const float* b0 = (const float*)d_in[3];
  const float* W1 = (const float*)d_in[4];
  const float* b1 = (const float*)d_in[5];
  float* out = (float*)d_out;
  const int* src = ei;        // edge_index[0] = message source
  const int* dst = ei + NE;   // edge_index[1] = aggregation target

  char* p = (char*)d_ws;
  int*   deg       = (int*)p;    p += 50048 * 4;
  float* dis       = (float*)p;  p += 50048 * 4;
  int*   row_start = (int*)p;    p += 50052 * 4;
  int*   cursor    = (int*)p;    p += 50048 * 4;
  int*   partial   = (int*)p;    p += 256 * 4;
  int*   perm      = (int*)p;    p += 50048 * 4;
  int*   csr       = (int*)p;    p += 1000064 * 4;   // padded: <= 850000 + 3*50000
  unsigned short* bufA = (unsigned short*)p;  // 4 panels x 1600032 halves (~12.8 MB)
  // sort scratch aliases bufA head (dead until first GEMM; dummy rows live at tail)
  int*   hist2     = (int*)bufA;          // 12544
  int*   partial2  = hist2 + NH2;         // 49

  // graph build (once, reused by both layers)
  k_init_deg<<<196, 256, 0, stream>>>(deg);
  k_count_part<<<NPART * BPP, 256, 0, stream>>>(dst, deg);
  k_blocksum_pad<<<NB, 256, 0, stream>>>(deg, partial);
  k_scanp<<<1, 256, 0, stream>>>(partial, NB);
  k_scatter<<<NB, 256, 0, stream>>>(deg, partial, row_start, cursor, dis);
  k_fill_part<<<NPART * BPP, 256, 0, stream>>>(src, dst, cursor, csr);
  k_pad<<<NB, 256, 0, stream>>>(deg, row_start, csr);

  // windowed degree counting-sort -> perm (+ dummy-row zeroing in k_hist2)
  hipMemsetAsync(hist2, 0, NH2 * 4, stream);
  k_hist2<<<196, 256, 0, stream>>>(deg, hist2, bufA);
  k_blocksum<<<NH2B, 256, 0, stream>>>(hist2, partial2, NH2);
  k_scanp<<<1, 256, 0, stream>>>(partial2, NH2B);
  k_excl<<<NH2B, 256, 0, stream>>>(hist2, partial2, NH2);
  k_perm2<<<196, 256, 0, stream>>>(deg, hist2, perm);

  const int AGG_GRID = NCH * ((NN + 63) / 64);   // 4 * 782 = 3128 blocks
  // layer 1
  k_gemm<<<(NN + GR - 1) / GR, 256, 0, stream>>>(x, W0, dis, bufA);
  k_agg<<<AGG_GRID, 256, 0, stream>>>(bufA, dis, row_start, csr, perm, b0, out);
  // layer 2
  k_gemm<<<(NN + GR - 1) / GR, 256, 0, stream>>>(out, W1, dis, bufA);
  k_agg<<<AGG_GRID, 256, 0, stream>>>(bufA, dis, row_start, csr, perm, b1, out);
}

// Round 11
// 242.046 us; speedup vs baseline: 1.6946x; 1.6946x over previous
//
#include <hip/hip_runtime.h>

#define NN 50000
#define NE 800000
#define EH (NE + NN)   // 850000 edges incl. self-loops
#define HD 128
#define NB 196         // ceil(NN/256)
#define NCH 4          // column chunks
#define CPW 32         // cols per chunk (bf16 row = 64 B = one cache line)
#define PSTRH ((NN + 1) * CPW)  // halves per panel = 1600032 (row NN = dummy zeros)
// windowed counting-sort: sort by degree WITHIN each 1024-node window
#define WLOG 10
#define NWIN 49
#define DBIN 64
#define DSUB 4
#define NH2 (NWIN * DBIN * DSUB)   // 12544 bins
#define NH2B ((NH2 + 255) / 256)   // 49 scan blocks

typedef __attribute__((ext_vector_type(8))) short bf16x8;
typedef __attribute__((ext_vector_type(4))) float f32x4;

__device__ __forceinline__ unsigned short f2bf(float f) {
  union { float f; unsigned int u; } v; v.f = f;
  unsigned int r = v.u + 0x7FFFu + ((v.u >> 16) & 1u);   // RNE
  return (unsigned short)(r >> 16);
}
__device__ __forceinline__ unsigned int pack2(float lo, float hi) {
  return (unsigned int)f2bf(lo) | ((unsigned int)f2bf(hi) << 16);
}

// ---------------- graph build (R9 version — known 58 µs fill) ----------------
__global__ void k_init_deg(int* __restrict__ deg) {
  int i = blockIdx.x * 256 + threadIdx.x;
  if (i < NN) deg[i] = 1;   // self-loop contributes 1
}

__global__ void k_count(const int* __restrict__ dst, int* __restrict__ deg) {
  int e = blockIdx.x * 256 + threadIdx.x;
  if (e < NE) atomicAdd(&deg[dst[e]], 1);
}

// per-block sums of PADDED degree ((d+3)&~3)
__global__ __launch_bounds__(256) void k_blocksum_pad(const int* __restrict__ deg,
                                                      int* __restrict__ partial) {
  int i = blockIdx.x * 256 + threadIdx.x;
  int v = (i < NN) ? ((deg[i] + 3) & ~3) : 0;
  #pragma unroll
  for (int off = 32; off >= 1; off >>= 1) v += __shfl_down(v, off);
  __shared__ int ws[4];
  if ((threadIdx.x & 63) == 0) ws[threadIdx.x >> 6] = v;
  __syncthreads();
  if (threadIdx.x == 0) partial[blockIdx.x] = ws[0] + ws[1] + ws[2] + ws[3];
}

__global__ __launch_bounds__(256) void k_blocksum(const int* __restrict__ in,
                                                  int* __restrict__ partial, int nelem) {
  int i = blockIdx.x * 256 + threadIdx.x;
  int v = (i < nelem) ? in[i] : 0;
  #pragma unroll
  for (int off = 32; off >= 1; off >>= 1) v += __shfl_down(v, off);
  __shared__ int ws[4];
  if ((threadIdx.x & 63) == 0) ws[threadIdx.x >> 6] = v;
  __syncthreads();
  if (threadIdx.x == 0) partial[blockIdx.x] = ws[0] + ws[1] + ws[2] + ws[3];
}

__global__ __launch_bounds__(256) void k_scanp(int* __restrict__ data, int n) {
  __shared__ int lds[256];
  int t = threadIdx.x;
  int v = (t < n) ? data[t] : 0;
  lds[t] = v;
  __syncthreads();
  #pragma unroll
  for (int off = 1; off < 256; off <<= 1) {
    int u = (t >= off) ? lds[t - off] : 0;
    __syncthreads();
    lds[t] += u;
    __syncthreads();
  }
  if (t < n) data[t] = lds[t] - v;   // exclusive
}

// row_start (padded, 4-aligned) / cursor + fused dis = rsqrt(real deg)
__global__ __launch_bounds__(256) void k_scatter(const int* __restrict__ deg,
                                                 const int* __restrict__ partial,
                                                 int* __restrict__ row_start,
                                                 int* __restrict__ cursor,
                                                 float* __restrict__ dis) {
  __shared__ int lds[256];
  int t = threadIdx.x;
  int i = blockIdx.x * 256 + t;
  int vr = (i < NN) ? deg[i] : 0;
  int v = (vr + 3) & ~3;
  lds[t] = v;
  __syncthreads();
  #pragma unroll
  for (int off = 1; off < 256; off <<= 1) {
    int u = (t >= off) ? lds[t - off] : 0;
    __syncthreads();
    lds[t] += u;
    __syncthreads();
  }
  int ex = lds[t] - v + partial[blockIdx.x];
  if (i < NN) {
    row_start[i] = ex;
    cursor[i] = ex;
    dis[i] = rsqrtf((float)vr);   // deg >= 1 always
    if (i == NN - 1) row_start[NN] = ex + v;
  }
}

__global__ void k_fill(const int* __restrict__ src, const int* __restrict__ dst,
                       int* __restrict__ cursor, int* __restrict__ csr_src) {
  int e = blockIdx.x * 256 + threadIdx.x;
  if (e >= EH) return;
  int s, d;
  if (e < NE) { s = src[e]; d = dst[e]; }
  else        { s = e - NE; d = s; }          // self-loop
  int pos = atomicAdd(&cursor[d], 1);
  csr_src[pos] = s;
}

// fill padding slots (up to 3 per node) with dummy row index NN
__global__ void k_pad(const int* __restrict__ deg, const int* __restrict__ row_start,
                      int* __restrict__ csr_src) {
  int n = blockIdx.x * 256 + threadIdx.x;
  if (n < NN) {
    int d = deg[n];
    int s = row_start[n] + d;
    int e = row_start[n] + ((d + 3) & ~3);
    for (int q = s; q < e; ++q) csr_src[q] = NN;
  }
}

// ------------- windowed degree counting-sort ----------------------------------
__device__ __forceinline__ int sort_bin(int i, int d) {
  if (d > DBIN - 1) d = DBIN - 1;
  return (((i >> WLOG) * DBIN + d) * DSUB) + (i & (DSUB - 1));
}

// also zeroes the panels' dummy rows (runs before any GEMM writes panels)
__global__ void k_hist2(const int* __restrict__ deg, int* __restrict__ h,
                        unsigned short* __restrict__ panels) {
  int i = blockIdx.x * 256 + threadIdx.x;
  if (i < NCH * CPW) {   // 128 threads zero 4 x 32 dummy halves
    int pl = i >> 5;
    panels[(size_t)pl * PSTRH + (size_t)NN * CPW + (i & 31)] = 0;
  }
  if (i < NN) atomicAdd(&h[sort_bin(i, deg[i])], 1);
}

__global__ __launch_bounds__(256) void k_excl(int* __restrict__ data,
                                              const int* __restrict__ partial, int nelem) {
  __shared__ int lds[256];
  int t = threadIdx.x;
  int i = blockIdx.x * 256 + t;
  int v = (i < nelem) ? data[i] : 0;
  lds[t] = v;
  __syncthreads();
  #pragma unroll
  for (int off = 1; off < 256; off <<= 1) {
    int u = (t >= off) ? lds[t - off] : 0;
    __syncthreads();
    lds[t] += u;
    __syncthreads();
  }
  if (i < nelem) data[i] = lds[t] - v + partial[blockIdx.x];
}

__global__ void k_perm2(const int* __restrict__ deg, int* __restrict__ h,
                        int* __restrict__ perm) {
  int i = blockIdx.x * 256 + threadIdx.x;
  if (i < NN) {
    int pos = atomicAdd(&h[sort_bin(i, deg[i])], 1);
    perm[pos] = i;
  }
}

// ---------------- W transpose prep: Wt[c][k] bf16 from W[k][c] f32 ---------------
__global__ void k_wprep(const float* __restrict__ W, unsigned short* __restrict__ Wt) {
  int t = blockIdx.x * 256 + threadIdx.x;   // 2048 threads
  int k = t >> 4, c0 = (t & 15) * 8;
  float4 v0 = ((const float4*)W)[(k * HD + c0) >> 2];
  float4 v1 = ((const float4*)W)[((k * HD + c0) >> 2) + 1];
  Wt[(c0 + 0) * HD + k] = f2bf(v0.x);
  Wt[(c0 + 1) * HD + k] = f2bf(v0.y);
  Wt[(c0 + 2) * HD + k] = f2bf(v0.z);
  Wt[(c0 + 3) * HD + k] = f2bf(v0.w);
  Wt[(c0 + 4) * HD + k] = f2bf(v1.x);
  Wt[(c0 + 5) * HD + k] = f2bf(v1.y);
  Wt[(c0 + 6) * HD + k] = f2bf(v1.z);
  Wt[(c0 + 7) * HD + k] = f2bf(v1.w);
}

// ------- MFMA GEMM: Cpanels(bf16) = dis[row] * (A[NN,128] @ W) ----------------
// A cast to bf16 at staging; W pre-transposed bf16 [col][k]. LDS XOR-swizzled
// (slot ^= row&7 per 16B slot) to kill the [*][128]-bf16 16-way bank conflict (G4).
// 4 waves: wave w owns rows [32w,32w+32); mfma_f32_16x16x32_bf16, f32 accum.
// C/D layout (m89): col=lane&15, row=(lane>>4)*4+reg.
#define GR 128
__global__ __launch_bounds__(256, 2) void k_gemm(const float* __restrict__ A,
                                                 const unsigned short* __restrict__ Wt,
                                                 const float* __restrict__ dis,
                                                 unsigned short* __restrict__ C) {
  __shared__ unsigned short Als[GR * HD];   // 32 KB, [row][k] swizzled
  __shared__ unsigned short Bls[HD * HD];   // 32 KB, [col][k] swizzled
  const int tid = threadIdx.x;
  const int r0 = blockIdx.x * GR;
  // stage A -> bf16 (8 floats per chunk, 2048 chunks)
  #pragma unroll
  for (int m = 0; m < 8; ++m) {
    int f = tid + m * 256;
    int row = f >> 4, j = f & 15;       // j = k/8
    int grow = r0 + row;
    float4 v0 = make_float4(0.f, 0.f, 0.f, 0.f), v1 = v0;
    if (grow < NN) {
      v0 = ((const float4*)A)[grow * 32 + j * 2];
      v1 = ((const float4*)A)[grow * 32 + j * 2 + 1];
    }
    uint4 u;
    u.x = pack2(v0.x, v0.y); u.y = pack2(v0.z, v0.w);
    u.z = pack2(v1.x, v1.y); u.w = pack2(v1.z, v1.w);
    int slot = j ^ (row & 7);
    *(uint4*)&Als[row * HD + slot * 8] = u;
  }
  // stage Wt (already bf16 [c][k], contiguous copy with swizzle)
  #pragma unroll
  for (int m = 0; m < 8; ++m) {
    int f = tid + m * 256;
    int c = f >> 4, j = f & 15;
    uint4 w = ((const uint4*)Wt)[f];
    int slot = j ^ (c & 7);
    *(uint4*)&Bls[c * HD + slot * 8] = w;
  }
  __syncthreads();

  const int w = tid >> 6, l = tid & 63;
  const int lm = l & 15, lg = l >> 4;
  const int rbase = w * 32;
  f32x4 acc[2][8] = {};
  #pragma unroll
  for (int ks = 0; ks < 4; ++ks) {
    int row0 = rbase + lm;
    int row1 = row0 + 16;
    bf16x8 a0 = *(const bf16x8*)&Als[row0 * HD + ((ks * 4 + lg) ^ (row0 & 7)) * 8];
    bf16x8 a1 = *(const bf16x8*)&Als[row1 * HD + ((ks * 4 + lg) ^ (row1 & 7)) * 8];
    #pragma unroll
    for (int ct = 0; ct < 8; ++ct) {
      int c = ct * 16 + lm;
      bf16x8 b = *(const bf16x8*)&Bls[c * HD + ((ks * 4 + lg) ^ (c & 7)) * 8];
      acc[0][ct] = __builtin_amdgcn_mfma_f32_16x16x32_bf16(a0, b, acc[0][ct], 0, 0, 0);
      acc[1][ct] = __builtin_amdgcn_mfma_f32_16x16x32_bf16(a1, b, acc[1][ct], 0, 0, 0);
    }
  }
  // epilogue: dis-scale, bf16, write panels (block covers full lines -> L2 coalesces)
  #pragma unroll
  for (int rt = 0; rt < 2; ++rt) {
    #pragma unroll
    for (int reg = 0; reg < 4; ++reg) {
      int row = r0 + rbase + rt * 16 + lg * 4 + reg;
      if (row < NN) {
        float dsc = dis[row];
        #pragma unroll
        for (int ct = 0; ct < 8; ++ct) {
          int col = ct * 16 + lm;
          C[(size_t)(col >> 5) * PSTRH + (size_t)row * CPW + (col & 31)] =
              f2bf(acc[rt][ct][reg] * dsc);
        }
      }
    }
  }
}

// ---------------- CSR gather-aggregate (bf16 panels, window-sorted) ---------------
__device__ __forceinline__ void bacc(float* a, uint4 q) {
  union { unsigned int u; float f; } t;
  t.u = q.x << 16;          a[0] += t.f;
  t.u = q.x & 0xFFFF0000u;  a[1] += t.f;
  t.u = q.y << 16;          a[2] += t.f;
  t.u = q.y & 0xFFFF0000u;  a[3] += t.f;
  t.u = q.z << 16;          a[4] += t.f;
  t.u = q.z & 0xFFFF0000u;  a[5] += t.f;
  t.u = q.w << 16;          a[6] += t.f;
  t.u = q.w & 0xFFFF0000u;  a[7] += t.f;
}

__global__ __launch_bounds__(256) void k_agg(const unsigned short* __restrict__ Tpanels,
                                             const float* __restrict__ dis,
                                             const int* __restrict__ row_start,
                                             const int* __restrict__ csr_src,
                                             const int* __restrict__ perm,
                                             const float* __restrict__ bias,
                                             float* __restrict__ out) {
  const int tid = threadIdx.x;
  const int chunk = blockIdx.x & (NCH - 1);
  const int idx = (blockIdx.x >> 2) * 64 + (tid >> 2);
  if (idx >= NN) return;
  const int n = perm[idx];
  const int c8 = tid & 3;                       // 8-col slot within chunk
  const unsigned short* __restrict__ P = Tpanels + (size_t)chunk * PSTRH;
  const int4* __restrict__ csr4 = (const int4*)csr_src;

  const int jb = row_start[n] >> 2, je = row_start[n + 1] >> 2;   // 4-aligned
  float a0[8] = {0,0,0,0,0,0,0,0};
  float a1[8] = {0,0,0,0,0,0,0,0};
  int j = jb;
  for (; j + 2 <= je; j += 2) {
    int4 sA = csr4[j], sB = csr4[j + 1];
    uint4 q0 = *(const uint4*)&P[(size_t)sA.x * CPW + c8 * 8];
    uint4 q1 = *(const uint4*)&P[(size_t)sA.y * CPW + c8 * 8];
    uint4 q2 = *(const uint4*)&P[(size_t)sA.z * CPW + c8 * 8];
    uint4 q3 = *(const uint4*)&P[(size_t)sA.w * CPW + c8 * 8];
    uint4 q4 = *(const uint4*)&P[(size_t)sB.x * CPW + c8 * 8];
    uint4 q5 = *(const uint4*)&P[(size_t)sB.y * CPW + c8 * 8];
    uint4 q6 = *(const uint4*)&P[(size_t)sB.z * CPW + c8 * 8];
    uint4 q7 = *(const uint4*)&P[(size_t)sB.w * CPW + c8 * 8];
    bacc(a0, q0); bacc(a1, q1); bacc(a0, q2); bacc(a1, q3);
    bacc(a0, q4); bacc(a1, q5); bacc(a0, q6); bacc(a1, q7);
  }
  if (j < je) {
    int4 sA = csr4[j];
    uint4 q0 = *(const uint4*)&P[(size_t)sA.x * CPW + c8 * 8];
    uint4 q1 = *(const uint4*)&P[(size_t)sA.y * CPW + c8 * 8];
    uint4 q2 = *(const uint4*)&P[(size_t)sA.z * CPW + c8 * 8];
    uint4 q3 = *(const uint4*)&P[(size_t)sA.w * CPW + c8 * 8];
    bacc(a0, q0); bacc(a1, q1); bacc(a0, q2); bacc(a1, q3);
  }
  const float dn = dis[n];
  const int cb = chunk * CPW + c8 * 8;
  const float4 b0 = *(const float4*)&bias[cb];
  const float4 b1 = *(const float4*)&bias[cb + 4];
  float r[8];
  #pragma unroll
  for (int i = 0; i < 8; ++i) r[i] = (a0[i] + a1[i]) * dn;
  r[0] += b0.x; r[1] += b0.y; r[2] += b0.z; r[3] += b0.w;
  r[4] += b1.x; r[5] += b1.y; r[6] += b1.z; r[7] += b1.w;
  #pragma unroll
  for (int i = 0; i < 8; ++i) r[i] = (r[i] >= 0.f) ? r[i] : 0.01f * r[i];
  float* o = out + (size_t)n * HD + cb;
  *(float4*)o = make_float4(r[0], r[1], r[2], r[3]);
  *(float4*)(o + 4) = make_float4(r[4], r[5], r[6], r[7]);
}

extern "C" void kernel_launch(void* const* d_in, const int* in_sizes, int n_in,
                              void* d_out, int out_size, void* d_ws, size_t ws_size,
                              hipStream_t stream) {
  const float* x  = (const float*)d_in[0];
  const int*   ei = (const int*)d_in[1];
  const float* W0 = (const float*)d_in[2];
  const float* b0 = (const float*)d_in[3];
  const float* W1 = (const float*)d_in[4];
  const float* b1 = (const float*)d_in[5];
  float* out = (float*)d_out;
  const int* src = ei;        // edge_index[0] = message source
  const int* dst = ei + NE;   // edge_index[1] = aggregation target

  char* p = (char*)d_ws;
  int*   deg       = (int*)p;    p += 50048 * 4;
  float* dis       = (float*)p;  p += 50048 * 4;
  int*   row_start = (int*)p;    p += 50052 * 4;
  int*   cursor    = (int*)p;    p += 50048 * 4;
  int*   partial   = (int*)p;    p += 256 * 4;
  int*   perm      = (int*)p;    p += 50048 * 4;
  int*   csr       = (int*)p;    p += 1000064 * 4;   // padded: <= 850000 + 3*50000
  unsigned short* wt0 = (unsigned short*)p; p += 16384 * 2;
  unsigned short* wt1 = (unsigned short*)p; p += 16384 * 2;
  unsigned short* bufA = (unsigned short*)p;  // 4 panels x 1600032 halves (~12.8 MB)
  // sort scratch aliases bufA head (dead until first GEMM; dummy rows live at tail)
  int*   hist2     = (int*)bufA;          // 12544
  int*   partial2  = hist2 + NH2;         // 49

  // graph build (once, reused by both layers)
  k_init_deg<<<196, 256, 0, stream>>>(deg);
  k_count<<<3125, 256, 0, stream>>>(dst, deg);
  k_blocksum_pad<<<NB, 256, 0, stream>>>(deg, partial);
  k_scanp<<<1, 256, 0, stream>>>(partial, NB);
  k_scatter<<<NB, 256, 0, stream>>>(deg, partial, row_start, cursor, dis);
  k_fill<<<(EH + 255) / 256, 256, 0, stream>>>(src, dst, cursor, csr);
  k_pad<<<NB, 256, 0, stream>>>(deg, row_start, csr);
  // W transposes (bf16)
  k_wprep<<<8, 256, 0, stream>>>(W0, wt0);
  k_wprep<<<8, 256, 0, stream>>>(W1, wt1);

  // windowed degree counting-sort -> perm (+ dummy-row zeroing in k_hist2)
  hipMemsetAsync(hist2, 0, NH2 * 4, stream);
  k_hist2<<<196, 256, 0, stream>>>(deg, hist2, bufA);
  k_blocksum<<<NH2B, 256, 0, stream>>>(hist2, partial2, NH2);
  k_scanp<<<1, 256, 0, stream>>>(partial2, NH2B);
  k_excl<<<NH2B, 256, 0, stream>>>(hist2, partial2, NH2);
  k_perm2<<<196, 256, 0, stream>>>(deg, hist2, perm);

  const int AGG_GRID = NCH * ((NN + 63) / 64);   // 4 * 782 = 3128 blocks
  // layer 1
  k_gemm<<<(NN + GR - 1) / GR, 256, 0, stream>>>(x, wt0, dis, bufA);
  k_agg<<<AGG_GRID, 256, 0, stream>>>(bufA, dis, row_start, csr, perm, b0, out);
  // layer 2
  k_gemm<<<(NN + GR - 1) / GR, 256, 0, stream>>>(out, wt1, dis, bufA);
  k_agg<<<AGG_GRID, 256, 0, stream>>>(bufA, dis, row_start, csr, perm, b1, out);
}

// Round 12
// 181.500 us; speedup vs baseline: 2.2599x; 1.3336x over previous
//
#include <hip/hip_runtime.h>

#define NN 50000
#define NE 800000
#define EH (NE + NN)   // 850000 edges incl. self-loops
#define HD 128
#define NB 196         // ceil(NN/256)
#define NCH 4          // column chunks
#define CPW 32         // cols per chunk (bf16 row = 64 B = one cache line)
#define PSTRH ((NN + 1) * CPW)  // halves per panel = 1600032 (row NN = dummy zeros)
// window structure (shared by bucket-build and counting-sort)
#define WLOG 10
#define NWIN 49        // ceil(NN/1024)
#define BKT 64         // bucket slots (49 used)
#define BCAP 20480     // per-bucket capacity (mean 17408, sigma~131 -> +23 sigma)
#define EPB 4096       // edges per k_bucket block
#define NBB 208        // ceil(EH/EPB)
// windowed counting-sort bins
#define DBIN 64
#define DSUB 4
#define NH2 (NWIN * DBIN * DSUB)   // 12544 bins
#define NH2B ((NH2 + 255) / 256)   // 49 scan blocks

typedef __attribute__((ext_vector_type(8))) short bf16x8;
typedef __attribute__((ext_vector_type(4))) float f32x4;

__device__ __forceinline__ unsigned short f2bf(float f) {
  union { float f; unsigned int u; } v; v.f = f;
  unsigned int r = v.u + 0x7FFFu + ((v.u >> 16) & 1u);   // RNE
  return (unsigned short)(r >> 16);
}
__device__ __forceinline__ unsigned int pack2(float lo, float hi) {
  return (unsigned int)f2bf(lo) | ((unsigned int)f2bf(hi) << 16);
}

// ---------------- phase 1: bucket edges by 1024-node window -------------------
// packed edge: src(16b) | dstlo(10b)<<16 | win(6b)<<26
__global__ __launch_bounds__(256) void k_bucket(const int* __restrict__ src,
                                                const int* __restrict__ dst,
                                                int* __restrict__ gcur,
                                                unsigned int* __restrict__ ebuf) {
  __shared__ unsigned int stage[EPB];     // 16 KB
  __shared__ int cnt[BKT], base[BKT], lcur[BKT], gbase[BKT];
  __shared__ int sTotal;
  const int tid = threadIdx.x;
  const int e0 = blockIdx.x * EPB;
  for (int i = tid; i < BKT; i += 256) cnt[i] = 0;
  __syncthreads();
  unsigned int myv[EPB / 256];
  #pragma unroll
  for (int m = 0; m < EPB / 256; ++m) {
    int e = e0 + m * 256 + tid;
    unsigned int v = 0;
    if (e < EH) {
      int s, d;
      if (e < NE) { s = src[e]; d = dst[e]; }
      else        { s = e - NE; d = s; }
      v = (unsigned int)s | ((unsigned int)(d & 1023) << 16)
        | ((unsigned int)(d >> WLOG) << 26);
      atomicAdd(&cnt[d >> WLOG], 1);
    }
    myv[m] = v;
  }
  __syncthreads();
  if (tid < 64) {
    int c = cnt[tid];
    int v = c;
    #pragma unroll
    for (int off = 1; off < 64; off <<= 1) {
      int u = __shfl_up(v, off);
      if ((tid & 63) >= off) v += u;
    }
    base[tid] = v - c;          // exclusive
    lcur[tid] = v - c;
    gbase[tid] = c ? atomicAdd(&gcur[tid], c) : 0;
    if (tid == 63) sTotal = v;
  }
  __syncthreads();
  #pragma unroll
  for (int m = 0; m < EPB / 256; ++m) {
    int e = e0 + m * 256 + tid;
    if (e < EH) {
      unsigned int v = myv[m];
      int pos = atomicAdd(&lcur[v >> 26], 1);
      stage[pos] = v;
    }
  }
  __syncthreads();
  const int total = sTotal;
  for (int s = tid; s < total; s += 256) {
    unsigned int v = stage[s];
    int b = v >> 26;
    ebuf[(size_t)b * BCAP + gbase[b] + (s - base[b])] = v;
  }
}

// ---------------- phase 2a: per-window degree histogram -----------------------
__global__ __launch_bounds__(1024) void k_wdeg(const unsigned int* __restrict__ ebuf,
                                               const int* __restrict__ gcur,
                                               int* __restrict__ deg) {
  __shared__ int h[1024];
  const int b = blockIdx.x;
  const int tid = threadIdx.x;
  h[tid] = 0;
  __syncthreads();
  const int n = gcur[b];
  const unsigned int* eb = ebuf + (size_t)b * BCAP;
  for (int i = tid; i < n; i += 1024) atomicAdd(&h[(eb[i] >> 16) & 1023], 1);
  __syncthreads();
  int node = b * 1024 + tid;
  if (node < NN) deg[node] = h[tid];   // self-loops already included as edges
}

// per-block sums of PADDED degree ((d+3)&~3)
__global__ __launch_bounds__(256) void k_blocksum_pad(const int* __restrict__ deg,
                                                      int* __restrict__ partial) {
  int i = blockIdx.x * 256 + threadIdx.x;
  int v = (i < NN) ? ((deg[i] + 3) & ~3) : 0;
  #pragma unroll
  for (int off = 32; off >= 1; off >>= 1) v += __shfl_down(v, off);
  __shared__ int ws[4];
  if ((threadIdx.x & 63) == 0) ws[threadIdx.x >> 6] = v;
  __syncthreads();
  if (threadIdx.x == 0) partial[blockIdx.x] = ws[0] + ws[1] + ws[2] + ws[3];
}

__global__ __launch_bounds__(256) void k_blocksum(const int* __restrict__ in,
                                                  int* __restrict__ partial, int nelem) {
  int i = blockIdx.x * 256 + threadIdx.x;
  int v = (i < nelem) ? in[i] : 0;
  #pragma unroll
  for (int off = 32; off >= 1; off >>= 1) v += __shfl_down(v, off);
  __shared__ int ws[4];
  if ((threadIdx.x & 63) == 0) ws[threadIdx.x >> 6] = v;
  __syncthreads();
  if (threadIdx.x == 0) partial[blockIdx.x] = ws[0] + ws[1] + ws[2] + ws[3];
}

__global__ __launch_bounds__(256) void k_scanp(int* __restrict__ data, int n) {
  __shared__ int lds[256];
  int t = threadIdx.x;
  int v = (t < n) ? data[t] : 0;
  lds[t] = v;
  __syncthreads();
  #pragma unroll
  for (int off = 1; off < 256; off <<= 1) {
    int u = (t >= off) ? lds[t - off] : 0;
    __syncthreads();
    lds[t] += u;
    __syncthreads();
  }
  if (t < n) data[t] = lds[t] - v;   // exclusive
}

// row_start (padded, 4-aligned) + fused dis = rsqrt(real deg)
__global__ __launch_bounds__(256) void k_scatter(const int* __restrict__ deg,
                                                 const int* __restrict__ partial,
                                                 int* __restrict__ row_start,
                                                 float* __restrict__ dis) {
  __shared__ int lds[256];
  int t = threadIdx.x;
  int i = blockIdx.x * 256 + t;
  int vr = (i < NN) ? deg[i] : 0;
  int v = (vr + 3) & ~3;
  lds[t] = v;
  __syncthreads();
  #pragma unroll
  for (int off = 1; off < 256; off <<= 1) {
    int u = (t >= off) ? lds[t - off] : 0;
    __syncthreads();
    lds[t] += u;
    __syncthreads();
  }
  int ex = lds[t] - v + partial[blockIdx.x];
  if (i < NN) {
    row_start[i] = ex;
    dis[i] = rsqrtf((float)vr);   // deg >= 1 always
    if (i == NN - 1) row_start[NN] = ex + v;
  }
}

// ---------------- phase 2b: per-window CSR fill (single-block owner) ----------
__global__ __launch_bounds__(1024) void k_wfill(const unsigned int* __restrict__ ebuf,
                                                const int* __restrict__ gcur,
                                                const int* __restrict__ row_start,
                                                int* __restrict__ csr_src) {
  __shared__ int cur[1024];
  const int b = blockIdx.x;
  const int tid = threadIdx.x;
  int node = b * 1024 + tid;
  cur[tid] = (node < NN) ? row_start[node] : 0;
  __syncthreads();
  const int n = gcur[b];
  const unsigned int* eb = ebuf + (size_t)b * BCAP;
  for (int i = tid; i < n; i += 1024) {
    unsigned int v = eb[i];
    int pos = atomicAdd(&cur[(v >> 16) & 1023], 1);
    csr_src[pos] = v & 0xFFFFu;
  }
}

// fill padding slots (up to 3 per node) with dummy row index NN
__global__ void k_pad(const int* __restrict__ deg, const int* __restrict__ row_start,
                      int* __restrict__ csr_src) {
  int n = blockIdx.x * 256 + threadIdx.x;
  if (n < NN) {
    int d = deg[n];
    int s = row_start[n] + d;
    int e = row_start[n] + ((d + 3) & ~3);
    for (int q = s; q < e; ++q) csr_src[q] = NN;
  }
}

// ------------- windowed degree counting-sort ----------------------------------
__device__ __forceinline__ int sort_bin(int i, int d) {
  if (d > DBIN - 1) d = DBIN - 1;
  return (((i >> WLOG) * DBIN + d) * DSUB) + (i & (DSUB - 1));
}

// also zeroes the panels' dummy rows (runs before any GEMM writes panels)
__global__ void k_hist2(const int* __restrict__ deg, int* __restrict__ h,
                        unsigned short* __restrict__ panels) {
  int i = blockIdx.x * 256 + threadIdx.x;
  if (i < NCH * CPW) {   // 128 threads zero 4 x 32 dummy halves
    int pl = i >> 5;
    panels[(size_t)pl * PSTRH + (size_t)NN * CPW + (i & 31)] = 0;
  }
  if (i < NN) atomicAdd(&h[sort_bin(i, deg[i])], 1);
}

__global__ __launch_bounds__(256) void k_excl(int* __restrict__ data,
                                              const int* __restrict__ partial, int nelem) {
  __shared__ int lds[256];
  int t = threadIdx.x;
  int i = blockIdx.x * 256 + t;
  int v = (i < nelem) ? data[i] : 0;
  lds[t] = v;
  __syncthreads();
  #pragma unroll
  for (int off = 1; off < 256; off <<= 1) {
    int u = (t >= off) ? lds[t - off] : 0;
    __syncthreads();
    lds[t] += u;
    __syncthreads();
  }
  if (i < nelem) data[i] = lds[t] - v + partial[blockIdx.x];
}

__global__ void k_perm2(const int* __restrict__ deg, int* __restrict__ h,
                        int* __restrict__ perm) {
  int i = blockIdx.x * 256 + threadIdx.x;
  if (i < NN) {
    int pos = atomicAdd(&h[sort_bin(i, deg[i])], 1);
    perm[pos] = i;
  }
}

// ---------------- W transpose prep: Wt[c][k] bf16 from W[k][c] f32 ---------------
__global__ void k_wprep(const float* __restrict__ W, unsigned short* __restrict__ Wt) {
  int t = blockIdx.x * 256 + threadIdx.x;   // 2048 threads
  int k = t >> 4, c0 = (t & 15) * 8;
  float4 v0 = ((const float4*)W)[(k * HD + c0) >> 2];
  float4 v1 = ((const float4*)W)[((k * HD + c0) >> 2) + 1];
  Wt[(c0 + 0) * HD + k] = f2bf(v0.x);
  Wt[(c0 + 1) * HD + k] = f2bf(v0.y);
  Wt[(c0 + 2) * HD + k] = f2bf(v0.z);
  Wt[(c0 + 3) * HD + k] = f2bf(v0.w);
  Wt[(c0 + 4) * HD + k] = f2bf(v1.x);
  Wt[(c0 + 5) * HD + k] = f2bf(v1.y);
  Wt[(c0 + 6) * HD + k] = f2bf(v1.z);
  Wt[(c0 + 7) * HD + k] = f2bf(v1.w);
}

// ------- MFMA GEMM: Cpanels(bf16) = dis[row] * (A[NN,128] @ W) ----------------
#define GR 128
__global__ __launch_bounds__(256, 2) void k_gemm(const float* __restrict__ A,
                                                 const unsigned short* __restrict__ Wt,
                                                 const float* __restrict__ dis,
                                                 unsigned short* __restrict__ C) {
  __shared__ unsigned short Als[GR * HD];   // 32 KB, [row][k] swizzled
  __shared__ unsigned short Bls[HD * HD];   // 32 KB, [col][k] swizzled
  const int tid = threadIdx.x;
  const int r0 = blockIdx.x * GR;
  #pragma unroll
  for (int m = 0; m < 8; ++m) {
    int f = tid + m * 256;
    int row = f >> 4, j = f & 15;       // j = k/8
    int grow = r0 + row;
    float4 v0 = make_float4(0.f, 0.f, 0.f, 0.f), v1 = v0;
    if (grow < NN) {
      v0 = ((const float4*)A)[grow * 32 + j * 2];
      v1 = ((const float4*)A)[grow * 32 + j * 2 + 1];
    }
    uint4 u;
    u.x = pack2(v0.x, v0.y); u.y = pack2(v0.z, v0.w);
    u.z = pack2(v1.x, v1.y); u.w = pack2(v1.z, v1.w);
    int slot = j ^ (row & 7);
    *(uint4*)&Als[row * HD + slot * 8] = u;
  }
  #pragma unroll
  for (int m = 0; m < 8; ++m) {
    int f = tid + m * 256;
    int c = f >> 4, j = f & 15;
    uint4 w = ((const uint4*)Wt)[f];
    int slot = j ^ (c & 7);
    *(uint4*)&Bls[c * HD + slot * 8] = w;
  }
  __syncthreads();

  const int w = tid >> 6, l = tid & 63;
  const int lm = l & 15, lg = l >> 4;
  const int rbase = w * 32;
  f32x4 acc[2][8] = {};
  #pragma unroll
  for (int ks = 0; ks < 4; ++ks) {
    int row0 = rbase + lm;
    int row1 = row0 + 16;
    bf16x8 a0 = *(const bf16x8*)&Als[row0 * HD + ((ks * 4 + lg) ^ (row0 & 7)) * 8];
    bf16x8 a1 = *(const bf16x8*)&Als[row1 * HD + ((ks * 4 + lg) ^ (row1 & 7)) * 8];
    #pragma unroll
    for (int ct = 0; ct < 8; ++ct) {
      int c = ct * 16 + lm;
      bf16x8 b = *(const bf16x8*)&Bls[c * HD + ((ks * 4 + lg) ^ (c & 7)) * 8];
      acc[0][ct] = __builtin_amdgcn_mfma_f32_16x16x32_bf16(a0, b, acc[0][ct], 0, 0, 0);
      acc[1][ct] = __builtin_amdgcn_mfma_f32_16x16x32_bf16(a1, b, acc[1][ct], 0, 0, 0);
    }
  }
  #pragma unroll
  for (int rt = 0; rt < 2; ++rt) {
    #pragma unroll
    for (int reg = 0; reg < 4; ++reg) {
      int row = r0 + rbase + rt * 16 + lg * 4 + reg;
      if (row < NN) {
        float dsc = dis[row];
        #pragma unroll
        for (int ct = 0; ct < 8; ++ct) {
          int col = ct * 16 + lm;
          C[(size_t)(col >> 5) * PSTRH + (size_t)row * CPW + (col & 31)] =
              f2bf(acc[rt][ct][reg] * dsc);
        }
      }
    }
  }
}

// ---------------- CSR gather-aggregate (bf16 panels, window-sorted) ---------------
__device__ __forceinline__ void bacc(float* a, uint4 q) {
  union { unsigned int u; float f; } t;
  t.u = q.x << 16;          a[0] += t.f;
  t.u = q.x & 0xFFFF0000u;  a[1] += t.f;
  t.u = q.y << 16;          a[2] += t.f;
  t.u = q.y & 0xFFFF0000u;  a[3] += t.f;
  t.u = q.z << 16;          a[4] += t.f;
  t.u = q.z & 0xFFFF0000u;  a[5] += t.f;
  t.u = q.w << 16;          a[6] += t.f;
  t.u = q.w & 0xFFFF0000u;  a[7] += t.f;
}

__global__ __launch_bounds__(256) void k_agg(const unsigned short* __restrict__ Tpanels,
                                             const float* __restrict__ dis,
                                             const int* __restrict__ row_start,
                                             const int* __restrict__ csr_src,
                                             const int* __restrict__ perm,
                                             const float* __restrict__ bias,
                                             float* __restrict__ out) {
  const int tid = threadIdx.x;
  const int chunk = blockIdx.x & (NCH - 1);
  const int idx = (blockIdx.x >> 2) * 64 + (tid >> 2);
  if (idx >= NN) return;
  const int n = perm[idx];
  const int c8 = tid & 3;                       // 8-col slot within chunk
  const unsigned short* __restrict__ P = Tpanels + (size_t)chunk * PSTRH;
  const int4* __restrict__ csr4 = (const int4*)csr_src;

  const int jb = row_start[n] >> 2, je = row_start[n + 1] >> 2;   // 4-aligned
  float a0[8] = {0,0,0,0,0,0,0,0};
  float a1[8] = {0,0,0,0,0,0,0,0};
  int j = jb;
  for (; j + 2 <= je; j += 2) {
    int4 sA = csr4[j], sB = csr4[j + 1];
    uint4 q0 = *(const uint4*)&P[(size_t)sA.x * CPW + c8 * 8];
    uint4 q1 = *(const uint4*)&P[(size_t)sA.y * CPW + c8 * 8];
    uint4 q2 = *(const uint4*)&P[(size_t)sA.z * CPW + c8 * 8];
    uint4 q3 = *(const uint4*)&P[(size_t)sA.w * CPW + c8 * 8];
    uint4 q4 = *(const uint4*)&P[(size_t)sB.x * CPW + c8 * 8];
    uint4 q5 = *(const uint4*)&P[(size_t)sB.y * CPW + c8 * 8];
    uint4 q6 = *(const uint4*)&P[(size_t)sB.z * CPW + c8 * 8];
    uint4 q7 = *(const uint4*)&P[(size_t)sB.w * CPW + c8 * 8];
    bacc(a0, q0); bacc(a1, q1); bacc(a0, q2); bacc(a1, q3);
    bacc(a0, q4); bacc(a1, q5); bacc(a0, q6); bacc(a1, q7);
  }
  if (j < je) {
    int4 sA = csr4[j];
    uint4 q0 = *(const uint4*)&P[(size_t)sA.x * CPW + c8 * 8];
    uint4 q1 = *(const uint4*)&P[(size_t)sA.y * CPW + c8 * 8];
    uint4 q2 = *(const uint4*)&P[(size_t)sA.z * CPW + c8 * 8];
    uint4 q3 = *(const uint4*)&P[(size_t)sA.w * CPW + c8 * 8];
    bacc(a0, q0); bacc(a1, q1); bacc(a0, q2); bacc(a1, q3);
  }
  const float dn = dis[n];
  const int cb = chunk * CPW + c8 * 8;
  const float4 b0 = *(const float4*)&bias[cb];
  const float4 b1 = *(const float4*)&bias[cb + 4];
  float r[8];
  #pragma unroll
  for (int i = 0; i < 8; ++i) r[i] = (a0[i] + a1[i]) * dn;
  r[0] += b0.x; r[1] += b0.y; r[2] += b0.z; r[3] += b0.w;
  r[4] += b1.x; r[5] += b1.y; r[6] += b1.z; r[7] += b1.w;
  #pragma unroll
  for (int i = 0; i < 8; ++i) r[i] = (r[i] >= 0.f) ? r[i] : 0.01f * r[i];
  float* o = out + (size_t)n * HD + cb;
  *(float4*)o = make_float4(r[0], r[1], r[2], r[3]);
  *(float4*)(o + 4) = make_float4(r[4], r[5], r[6], r[7]);
}

extern "C" void kernel_launch(void* const* d_in, const int* in_sizes, int n_in,
                              void* d_out, int out_size, void* d_ws, size_t ws_size,
                              hipStream_t stream) {
  const float* x  = (const float*)d_in[0];
  const int*   ei = (const int*)d_in[1];
  const float* W0 = (const float*)d_in[2];
  const float* b0 = (const float*)d_in[3];
  const float* W1 = (const float*)d_in[4];
  const float* b1 = (const float*)d_in[5];
  float* out = (float*)d_out;
  const int* src = ei;        // edge_index[0] = message source
  const int* dst = ei + NE;   // edge_index[1] = aggregation target

  char* p = (char*)d_ws;
  int*   deg       = (int*)p;    p += 50048 * 4;
  float* dis       = (float*)p;  p += 50048 * 4;
  int*   row_start = (int*)p;    p += 50052 * 4;
  int*   partial   = (int*)p;    p += 256 * 4;
  int*   perm      = (int*)p;    p += 50048 * 4;
  int*   gcur      = (int*)p;    p += 64 * 4;
  int*   csr       = (int*)p;    p += 1000064 * 4;   // padded: <= 850000 + 3*50000
  unsigned int* ebuf = (unsigned int*)p; p += (size_t)BKT * BCAP * 4;  // 5.2 MB
  unsigned short* wt0 = (unsigned short*)p; p += 16384 * 2;
  unsigned short* wt1 = (unsigned short*)p; p += 16384 * 2;
  unsigned short* bufA = (unsigned short*)p;  // 4 panels x 1600032 halves (~12.8 MB)
  // sort scratch aliases bufA head (dead until first GEMM; dummy rows live at tail)
  int*   hist2     = (int*)bufA;          // 12544
  int*   partial2  = hist2 + NH2;         // 49

  // ---- graph build: bucket once, window-owned count + fill ----
  hipMemsetAsync(gcur, 0, 64 * 4, stream);
  k_bucket<<<NBB, 256, 0, stream>>>(src, dst, gcur, ebuf);
  k_wdeg<<<NWIN, 1024, 0, stream>>>(ebuf, gcur, deg);
  k_blocksum_pad<<<NB, 256, 0, stream>>>(deg, partial);
  k_scanp<<<1, 256, 0, stream>>>(partial, NB);
  k_scatter<<<NB, 256, 0, stream>>>(deg, partial, row_start, dis);
  k_wfill<<<NWIN, 1024, 0, stream>>>(ebuf, gcur, row_start, csr);
  k_pad<<<NB, 256, 0, stream>>>(deg, row_start, csr);
  // W transposes (bf16)
  k_wprep<<<8, 256, 0, stream>>>(W0, wt0);
  k_wprep<<<8, 256, 0, stream>>>(W1, wt1);

  // windowed degree counting-sort -> perm (+ dummy-row zeroing in k_hist2)
  hipMemsetAsync(hist2, 0, NH2 * 4, stream);
  k_hist2<<<196, 256, 0, stream>>>(deg, hist2, bufA);
  k_blocksum<<<NH2B, 256, 0, stream>>>(hist2, partial2, NH2);
  k_scanp<<<1, 256, 0, stream>>>(partial2, NH2B);
  k_excl<<<NH2B, 256, 0, stream>>>(hist2, partial2, NH2);
  k_perm2<<<196, 256, 0, stream>>>(deg, hist2, perm);

  const int AGG_GRID = NCH * ((NN + 63) / 64);   // 4 * 782 = 3128 blocks
  // layer 1
  k_gemm<<<(NN + GR - 1) / GR, 256, 0, stream>>>(x, wt0, dis, bufA);
  k_agg<<<AGG_GRID, 256, 0, stream>>>(bufA, dis, row_start, csr, perm, b0, out);
  // layer 2
  k_gemm<<<(NN + GR - 1) / GR, 256, 0, stream>>>(out, wt1, dis, bufA);
  k_agg<<<AGG_GRID, 256, 0, stream>>>(bufA, dis, row_start, csr, perm, b1, out);
}

// Round 13
// 160.157 us; speedup vs baseline: 2.5611x; 1.1333x over previous
//
#include <hip/hip_runtime.h>

#define NN 50000
#define NE 800000
#define EH (NE + NN)   // 850000 edges incl. self-loops
#define HD 128
#define NCH 4          // column chunks
#define CPW 32         // cols per chunk (bf16 row = 64 B = one cache line)
#define PSTRH ((NN + 1) * CPW)  // halves per panel = 1600032 (row NN = dummy zeros)
// window structure
#define WLOG 10
#define NWIN 49        // ceil(NN/1024)
#define NSLOT (NWIN * 1024)   // 50176 perm slots (window-strided)
#define BKT 64
#define BCAP 20480
#define EPB 4096
#define NBB 208        // ceil(EH/EPB)

typedef __attribute__((ext_vector_type(8))) short bf16x8;
typedef __attribute__((ext_vector_type(4))) float f32x4;

__device__ __forceinline__ unsigned short f2bf(float f) {
  union { float f; unsigned int u; } v; v.f = f;
  unsigned int r = v.u + 0x7FFFu + ((v.u >> 16) & 1u);   // RNE
  return (unsigned short)(r >> 16);
}
__device__ __forceinline__ unsigned int pack2(float lo, float hi) {
  return (unsigned int)f2bf(lo) | ((unsigned int)f2bf(hi) << 16);
}

// ---------------- phase 1: bucket edges by 1024-node window -------------------
// packed edge: src(16b) | dstlo(10b)<<16 | win(6b)<<26
__global__ __launch_bounds__(256) void k_bucket(const int* __restrict__ src,
                                                const int* __restrict__ dst,
                                                int* __restrict__ gcur,
                                                unsigned int* __restrict__ ebuf) {
  __shared__ unsigned int stage[EPB];     // 16 KB
  __shared__ int cnt[BKT], base[BKT], lcur[BKT], gbase[BKT];
  __shared__ int sTotal;
  const int tid = threadIdx.x;
  const int e0 = blockIdx.x * EPB;
  for (int i = tid; i < BKT; i += 256) cnt[i] = 0;
  __syncthreads();
  unsigned int myv[EPB / 256];
  #pragma unroll
  for (int m = 0; m < EPB / 256; ++m) {
    int e = e0 + m * 256 + tid;
    unsigned int v = 0;
    if (e < EH) {
      int s, d;
      if (e < NE) { s = src[e]; d = dst[e]; }
      else        { s = e - NE; d = s; }
      v = (unsigned int)s | ((unsigned int)(d & 1023) << 16)
        | ((unsigned int)(d >> WLOG) << 26);
      atomicAdd(&cnt[d >> WLOG], 1);
    }
    myv[m] = v;
  }
  __syncthreads();
  if (tid < 64) {
    int c = cnt[tid];
    int v = c;
    #pragma unroll
    for (int off = 1; off < 64; off <<= 1) {
      int u = __shfl_up(v, off);
      if ((tid & 63) >= off) v += u;
    }
    base[tid] = v - c;          // exclusive
    lcur[tid] = v - c;
    gbase[tid] = c ? atomicAdd(&gcur[tid], c) : 0;
    if (tid == 63) sTotal = v;
  }
  __syncthreads();
  #pragma unroll
  for (int m = 0; m < EPB / 256; ++m) {
    int e = e0 + m * 256 + tid;
    if (e < EH) {
      unsigned int v = myv[m];
      int pos = atomicAdd(&lcur[v >> 26], 1);
      stage[pos] = v;
    }
  }
  __syncthreads();
  const int total = sTotal;
  for (int s = tid; s < total; s += 256) {
    unsigned int v = stage[s];
    int b = v >> 26;
    ebuf[(size_t)b * BCAP + gbase[b] + (s - base[b])] = v;
  }
}

// ------- phase 2a: per-window degree + counting-sort perm + padded partial --------
__global__ __launch_bounds__(1024) void k_wdegsort(const unsigned int* __restrict__ ebuf,
                                                   const int* __restrict__ gcur,
                                                   int* __restrict__ deg,
                                                   int* __restrict__ partial,
                                                   int* __restrict__ perm) {
  __shared__ int h[1024];
  __shared__ int cnt[64], base[64];
  __shared__ int red[16];
  const int b = blockIdx.x, tid = threadIdx.x;
  h[tid] = 0;
  if (tid < 64) cnt[tid] = 0;
  __syncthreads();
  const int n = gcur[b];
  const unsigned int* eb = ebuf + (size_t)b * BCAP;
  for (int i = tid; i < n; i += 1024) atomicAdd(&h[(eb[i] >> 16) & 1023], 1);
  __syncthreads();
  const int node = b * 1024 + tid;
  const bool valid = node < NN;
  const int d = valid ? h[tid] : 0;
  if (valid) deg[node] = d;
  perm[b * 1024 + tid] = NN;                  // init unused slots
  // padded-degree window sum
  int s = valid ? ((d + 3) & ~3) : 0;
  #pragma unroll
  for (int off = 32; off >= 1; off >>= 1) s += __shfl_down(s, off);
  if ((tid & 63) == 0) red[tid >> 6] = s;
  const int dc = d > 63 ? 63 : d;
  int sub = 0;
  if (valid) sub = atomicAdd(&cnt[dc], 1);
  __syncthreads();
  if (tid == 0) {
    int t2 = 0;
    #pragma unroll
    for (int i = 0; i < 16; ++i) t2 += red[i];
    partial[b] = t2;
  }
  if (tid < 64) {
    int c = cnt[tid], v = c;
    #pragma unroll
    for (int off = 1; off < 64; off <<= 1) {
      int u = __shfl_up(v, off);
      if (tid >= off) v += u;
    }
    base[tid] = v - c;
  }
  __syncthreads();
  if (valid) perm[b * 1024 + base[dc] + sub] = node;
}

// small exclusive scan (n <= 256)
__global__ __launch_bounds__(256) void k_scanp(int* __restrict__ data, int n) {
  __shared__ int lds[256];
  int t = threadIdx.x;
  int v = (t < n) ? data[t] : 0;
  lds[t] = v;
  __syncthreads();
  #pragma unroll
  for (int off = 1; off < 256; off <<= 1) {
    int u = (t >= off) ? lds[t - off] : 0;
    __syncthreads();
    lds[t] += u;
    __syncthreads();
  }
  if (t < n) data[t] = lds[t] - v;   // exclusive
}

// ------- phase 2b: per-window row_start (padded scan) + dis -----------------------
__global__ __launch_bounds__(1024) void k_wscatter(const int* __restrict__ deg,
                                                   const int* __restrict__ partial,
                                                   int* __restrict__ row_start,
                                                   float* __restrict__ dis) {
  __shared__ int lds[1024];
  const int b = blockIdx.x, tid = threadIdx.x;
  const int node = b * 1024 + tid;
  const int vr = (node < NN) ? deg[node] : 0;
  const int v = (vr + 3) & ~3;
  lds[tid] = v;
  __syncthreads();
  #pragma unroll
  for (int off = 1; off < 1024; off <<= 1) {
    int u = (tid >= off) ? lds[tid - off] : 0;
    __syncthreads();
    lds[tid] += u;
    __syncthreads();
  }
  int ex = lds[tid] - v + partial[b];
  if (node < NN) {
    row_start[node] = ex;
    dis[node] = rsqrtf((float)vr);   // deg >= 1 always
    if (node == NN - 1) row_start[NN] = ex + v;
  }
}

// ------- phase 2c: per-window CSR fill (u16) + pad fused --------------------------
__global__ __launch_bounds__(1024) void k_wfill(const unsigned int* __restrict__ ebuf,
                                                const int* __restrict__ gcur,
                                                const int* __restrict__ row_start,
                                                unsigned short* __restrict__ csr) {
  __shared__ int cur[1024];
  const int b = blockIdx.x, tid = threadIdx.x;
  const int node = b * 1024 + tid;
  const bool valid = node < NN;
  cur[tid] = valid ? row_start[node] : 0;
  __syncthreads();
  const int n = gcur[b];
  const unsigned int* eb = ebuf + (size_t)b * BCAP;
  for (int i = tid; i < n; i += 1024) {
    unsigned int v = eb[i];
    int pos = atomicAdd(&cur[(v >> 16) & 1023], 1);
    csr[pos] = (unsigned short)(v & 0xFFFFu);
  }
  __syncthreads();
  if (valid) {
    int e = row_start[node + 1];
    for (int q = cur[tid]; q < e; ++q) csr[q] = (unsigned short)NN;
  }
}

// ------- W transposes (both layers) + panel dummy-row zeroing ---------------------
__global__ void k_wprep(const float* __restrict__ W0, const float* __restrict__ W1,
                        unsigned short* __restrict__ wt0, unsigned short* __restrict__ wt1,
                        unsigned short* __restrict__ panels) {
  int t = blockIdx.x * 256 + threadIdx.x;   // 4096 threads
  if (t < NCH * CPW) {
    int pl = t >> 5;
    panels[(size_t)pl * PSTRH + (size_t)NN * CPW + (t & 31)] = 0;
  }
  const float* W = (t < 2048) ? W0 : W1;
  unsigned short* Wt = (t < 2048) ? wt0 : wt1;
  int tt = t & 2047;
  int k = tt >> 4, c0 = (tt & 15) * 8;
  float4 v0 = ((const float4*)W)[(k * HD + c0) >> 2];
  float4 v1 = ((const float4*)W)[((k * HD + c0) >> 2) + 1];
  Wt[(c0 + 0) * HD + k] = f2bf(v0.x);
  Wt[(c0 + 1) * HD + k] = f2bf(v0.y);
  Wt[(c0 + 2) * HD + k] = f2bf(v0.z);
  Wt[(c0 + 3) * HD + k] = f2bf(v0.w);
  Wt[(c0 + 4) * HD + k] = f2bf(v1.x);
  Wt[(c0 + 5) * HD + k] = f2bf(v1.y);
  Wt[(c0 + 6) * HD + k] = f2bf(v1.z);
  Wt[(c0 + 7) * HD + k] = f2bf(v1.w);
}

// ------- MFMA GEMM: Cpanels(bf16) = dis[row] * (A[NN,128] @ W) --------------------
// ABF16: A is bf16 (layer-2 h). Else f32, cast at staging.
#define GR 128
template<bool ABF16>
__global__ __launch_bounds__(256, 2) void k_gemm(const void* __restrict__ Ain,
                                                 const unsigned short* __restrict__ Wt,
                                                 const float* __restrict__ dis,
                                                 unsigned short* __restrict__ C) {
  __shared__ unsigned short Als[GR * HD];   // 32 KB, [row][k] swizzled
  __shared__ unsigned short Bls[HD * HD];   // 32 KB, [col][k] swizzled
  const int tid = threadIdx.x;
  const int r0 = blockIdx.x * GR;
  #pragma unroll
  for (int m = 0; m < 8; ++m) {
    int f = tid + m * 256;
    int row = f >> 4, j = f & 15;       // j = k/8
    int grow = r0 + row;
    uint4 u = make_uint4(0, 0, 0, 0);
    if (grow < NN) {
      if constexpr (ABF16) {
        u = ((const uint4*)Ain)[grow * 16 + j];
      } else {
        const float* A = (const float*)Ain;
        float4 v0 = ((const float4*)A)[grow * 32 + j * 2];
        float4 v1 = ((const float4*)A)[grow * 32 + j * 2 + 1];
        u.x = pack2(v0.x, v0.y); u.y = pack2(v0.z, v0.w);
        u.z = pack2(v1.x, v1.y); u.w = pack2(v1.z, v1.w);
      }
    }
    int slot = j ^ (row & 7);
    *(uint4*)&Als[row * HD + slot * 8] = u;
  }
  #pragma unroll
  for (int m = 0; m < 8; ++m) {
    int f = tid + m * 256;
    int c = f >> 4, j = f & 15;
    uint4 w = ((const uint4*)Wt)[f];
    int slot = j ^ (c & 7);
    *(uint4*)&Bls[c * HD + slot * 8] = w;
  }
  __syncthreads();

  const int w = tid >> 6, l = tid & 63;
  const int lm = l & 15, lg = l >> 4;
  const int rbase = w * 32;
  f32x4 acc[2][8] = {};
  #pragma unroll
  for (int ks = 0; ks < 4; ++ks) {
    int row0 = rbase + lm;
    int row1 = row0 + 16;
    bf16x8 a0 = *(const bf16x8*)&Als[row0 * HD + ((ks * 4 + lg) ^ (row0 & 7)) * 8];
    bf16x8 a1 = *(const bf16x8*)&Als[row1 * HD + ((ks * 4 + lg) ^ (row1 & 7)) * 8];
    #pragma unroll
    for (int ct = 0; ct < 8; ++ct) {
      int c = ct * 16 + lm;
      bf16x8 b = *(const bf16x8*)&Bls[c * HD + ((ks * 4 + lg) ^ (c & 7)) * 8];
      acc[0][ct] = __builtin_amdgcn_mfma_f32_16x16x32_bf16(a0, b, acc[0][ct], 0, 0, 0);
      acc[1][ct] = __builtin_amdgcn_mfma_f32_16x16x32_bf16(a1, b, acc[1][ct], 0, 0, 0);
    }
  }
  #pragma unroll
  for (int rt = 0; rt < 2; ++rt) {
    #pragma unroll
    for (int reg = 0; reg < 4; ++reg) {
      int row = r0 + rbase + rt * 16 + lg * 4 + reg;
      if (row < NN) {
        float dsc = dis[row];
        #pragma unroll
        for (int ct = 0; ct < 8; ++ct) {
          int col = ct * 16 + lm;
          C[(size_t)(col >> 5) * PSTRH + (size_t)row * CPW + (col & 31)] =
              f2bf(acc[rt][ct][reg] * dsc);
        }
      }
    }
  }
}

// ---------------- CSR gather-aggregate (bf16 panels, u16 csr, window-sorted) ------
__device__ __forceinline__ void bacc(float* a, uint4 q) {
  union { unsigned int u; float f; } t;
  t.u = q.x << 16;          a[0] += t.f;
  t.u = q.x & 0xFFFF0000u;  a[1] += t.f;
  t.u = q.y << 16;          a[2] += t.f;
  t.u = q.y & 0xFFFF0000u;  a[3] += t.f;
  t.u = q.z << 16;          a[4] += t.f;
  t.u = q.z & 0xFFFF0000u;  a[5] += t.f;
  t.u = q.w << 16;          a[6] += t.f;
  t.u = q.w & 0xFFFF0000u;  a[7] += t.f;
}

template<bool OBF16>
__global__ __launch_bounds__(256) void k_agg(const unsigned short* __restrict__ Tpanels,
                                             const float* __restrict__ dis,
                                             const int* __restrict__ row_start,
                                             const unsigned short* __restrict__ csr,
                                             const int* __restrict__ perm,
                                             const float* __restrict__ bias,
                                             void* __restrict__ outv) {
  const int tid = threadIdx.x;
  const int chunk = blockIdx.x & (NCH - 1);
  const int idx = (blockIdx.x >> 2) * 64 + (tid >> 2);
  const int n = perm[idx];
  if (n >= NN) return;                          // unused window-slot
  const int c8 = tid & 3;                       // 8-col slot within chunk
  const unsigned short* __restrict__ P = Tpanels + (size_t)chunk * PSTRH;
  const ushort4* __restrict__ csr4 = (const ushort4*)csr;

  const int jb = row_start[n] >> 2, je = row_start[n + 1] >> 2;   // 4-aligned
  float a0[8] = {0,0,0,0,0,0,0,0};
  float a1[8] = {0,0,0,0,0,0,0,0};
  int j = jb;
  for (; j + 2 <= je; j += 2) {
    ushort4 sA = csr4[j], sB = csr4[j + 1];
    uint4 q0 = *(const uint4*)&P[(size_t)sA.x * CPW + c8 * 8];
    uint4 q1 = *(const uint4*)&P[(size_t)sA.y * CPW + c8 * 8];
    uint4 q2 = *(const uint4*)&P[(size_t)sA.z * CPW + c8 * 8];
    uint4 q3 = *(const uint4*)&P[(size_t)sA.w * CPW + c8 * 8];
    uint4 q4 = *(const uint4*)&P[(size_t)sB.x * CPW + c8 * 8];
    uint4 q5 = *(const uint4*)&P[(size_t)sB.y * CPW + c8 * 8];
    uint4 q6 = *(const uint4*)&P[(size_t)sB.z * CPW + c8 * 8];
    uint4 q7 = *(const uint4*)&P[(size_t)sB.w * CPW + c8 * 8];
    bacc(a0, q0); bacc(a1, q1); bacc(a0, q2); bacc(a1, q3);
    bacc(a0, q4); bacc(a1, q5); bacc(a0, q6); bacc(a1, q7);
  }
  if (j < je) {
    ushort4 sA = csr4[j];
    uint4 q0 = *(const uint4*)&P[(size_t)sA.x * CPW + c8 * 8];
    uint4 q1 = *(const uint4*)&P[(size_t)sA.y * CPW + c8 * 8];
    uint4 q2 = *(const uint4*)&P[(size_t)sA.z * CPW + c8 * 8];
    uint4 q3 = *(const uint4*)&P[(size_t)sA.w * CPW + c8 * 8];
    bacc(a0, q0); bacc(a1, q1); bacc(a0, q2); bacc(a1, q3);
  }
  const float dn = dis[n];
  const int cb = chunk * CPW + c8 * 8;
  const float4 b0 = *(const float4*)&bias[cb];
  const float4 b1 = *(const float4*)&bias[cb + 4];
  float r[8];
  #pragma unroll
  for (int i = 0; i < 8; ++i) r[i] = (a0[i] + a1[i]) * dn;
  r[0] += b0.x; r[1] += b0.y; r[2] += b0.z; r[3] += b0.w;
  r[4] += b1.x; r[5] += b1.y; r[6] += b1.z; r[7] += b1.w;
  #pragma unroll
  for (int i = 0; i < 8; ++i) r[i] = (r[i] >= 0.f) ? r[i] : 0.01f * r[i];
  if constexpr (OBF16) {
    uint4 o;
    o.x = pack2(r[0], r[1]); o.y = pack2(r[2], r[3]);
    o.z = pack2(r[4], r[5]); o.w = pack2(r[6], r[7]);
    *(uint4*)((unsigned short*)outv + (size_t)n * HD + cb) = o;
  } else {
    float* o = (float*)outv + (size_t)n * HD + cb;
    *(float4*)o = make_float4(r[0], r[1], r[2], r[3]);
    *(float4*)(o + 4) = make_float4(r[4], r[5], r[6], r[7]);
  }
}

extern "C" void kernel_launch(void* const* d_in, const int* in_sizes, int n_in,
                              void* d_out, int out_size, void* d_ws, size_t ws_size,
                              hipStream_t stream) {
  const float* x  = (const float*)d_in[0];
  const int*   ei = (const int*)d_in[1];
  const float* W0 = (const float*)d_in[2];
  const float* b0 = (const float*)d_in[3];
  const float* W1 = (const float*)d_in[4];
  const float* b1 = (const float*)d_in[5];
  float* out = (float*)d_out;
  const int* src = ei;        // edge_index[0] = message source
  const int* dst = ei + NE;   // edge_index[1] = aggregation target

  char* p = (char*)d_ws;
  int*   deg       = (int*)p;    p += 50048 * 4;
  float* dis       = (float*)p;  p += 50048 * 4;
  int*   row_start = (int*)p;    p += 50052 * 4;
  int*   partial   = (int*)p;    p += 256 * 4;
  int*   perm      = (int*)p;    p += NSLOT * 4;        // 50176
  int*   gcur      = (int*)p;    p += 64 * 4;
  unsigned short* csr = (unsigned short*)p; p += 1000064 * 2;   // u16 CSR, 2 MB
  unsigned int* ebuf = (unsigned int*)p; p += (size_t)BKT * BCAP * 4;  // 5.2 MB
  unsigned short* wt0 = (unsigned short*)p; p += 16384 * 2;
  unsigned short* wt1 = (unsigned short*)p; p += 16384 * 2;
  unsigned short* h1  = (unsigned short*)p; p += (size_t)NN * HD * 2;  // bf16 h, 12.8 MB
  unsigned short* bufA = (unsigned short*)p;  // 4 panels x 1600032 halves (~12.8 MB)

  // ---- graph build: 5 kernels + 1 memset ----
  hipMemsetAsync(gcur, 0, 64 * 4, stream);
  k_bucket<<<NBB, 256, 0, stream>>>(src, dst, gcur, ebuf);
  k_wdegsort<<<NWIN, 1024, 0, stream>>>(ebuf, gcur, deg, partial, perm);
  k_scanp<<<1, 256, 0, stream>>>(partial, NWIN);
  k_wscatter<<<NWIN, 1024, 0, stream>>>(deg, partial, row_start, dis);
  k_wfill<<<NWIN, 1024, 0, stream>>>(ebuf, gcur, row_start, csr);
  k_wprep<<<16, 256, 0, stream>>>(W0, W1, wt0, wt1, bufA);

  const int AGG_GRID = NCH * (NSLOT / 64);   // 4 * 784 = 3136 blocks
  // layer 1: h1(bf16) = leaky(agg(gemm(x,W0)) + b0)  [bf16 store == gemm-2's staging rounding]
  k_gemm<false><<<(NN + GR - 1) / GR, 256, 0, stream>>>(x, wt0, dis, bufA);
  k_agg<true><<<AGG_GRID, 256, 0, stream>>>(bufA, dis, row_start, csr, perm, b0, h1);
  // layer 2: out(f32)
  k_gemm<true><<<(NN + GR - 1) / GR, 256, 0, stream>>>(h1, wt1, dis, bufA);
  k_agg<false><<<AGG_GRID, 256, 0, stream>>>(bufA, dis, row_start, csr, perm, b1, out);
}